// Round 7
// baseline (492.961 us; speedup 1.0000x reference)
//
#include <hip/hip_runtime.h>

#define TT   512
#define HD   18
#define NB   16          /* batches per block */
#define NTH  640         /* 10 waves: w0-4 = L1 tiles 0-4, w5-9 = L2 tiles 0-4 */
#define RS   68          /* LDS row stride in halves (136B, 8B-aligned) */

typedef _Float16 v8h __attribute__((ext_vector_type(8)));
typedef float    v4f __attribute__((ext_vector_type(4)));

__device__ __forceinline__ float fsig(float x) {
    return __builtin_amdgcn_rcpf(1.0f + __expf(-x));
}

// LDS rows (per buffer, per batch): k[0..17]=input (x or h1), k[18..35]=own h,
// k[36]=1.0 (bias column), rest 0.
// SH[0..3] = layer-1 x-ring/h1 (4-deep); SH[4..5] = layer-2 double buffer.

__global__ __launch_bounds__(NTH) void lstm2_mfma10(
    const float* __restrict__ x,
    const float* __restrict__ wih0, const float* __restrict__ whh0,
    const float* __restrict__ bih0, const float* __restrict__ bhh0,
    const float* __restrict__ wih1, const float* __restrict__ whh1,
    const float* __restrict__ bih1, const float* __restrict__ bhh1,
    float* __restrict__ out)
{
    __shared__ __align__(16) _Float16 SH[6][NB][RS];

    const int tid  = threadIdx.x;
    const int wid  = tid >> 6;
    const int lane = tid & 63;
    const size_t b0 = (size_t)blockIdx.x * NB;

    // ---- init: zero all, then bias columns + x[0..2] ----
    {
        uint* shw = (uint*)&SH[0][0][0];
        for (int i = tid; i < 6 * NB * RS / 2; i += NTH) shw[i] = 0u;
        __syncthreads();
        for (int i = tid; i < 6 * NB; i += NTH)
            SH[i / NB][i % NB][2 * HD] = (_Float16)1.0f;
        for (int i = tid; i < 3 * NB * HD; i += NTH) {
            const int t = i / (NB * HD), r2 = i % (NB * HD);
            const int b = r2 / HD, k = r2 % HD;
            SH[t][b][k] = (_Float16)x[(b0 + b) * (size_t)TT * HD + t * HD + k];
        }
    }

    const bool isl1 = (wid < 5);
    const int  tile = isl1 ? wid : wid - 5;
    const int  rl   = lane & 15;    // batch column
    const int  lg   = lane >> 4;    // k-group / h-subrow
    const int  hh   = 4 * tile + lg;

    const float* wih = isl1 ? wih0 : wih1;
    const float* whh = isl1 ? whh0 : whh1;
    const float* bi  = isl1 ? bih0 : bih1;
    const float* bh  = isl1 ? bhh0 : bhh1;

    // ---- A fragments: W'[row=4h+g][k], k: 0-17 wih, 18-35 whh, 36 bias ----
    v8h Af[2];
    {
        const int row = 16 * tile + rl;
        const int h = row >> 2, g = row & 3;
        const int r = g * HD + h;
        #pragma unroll
        for (int s = 0; s < 2; ++s) {
            v8h a;
            #pragma unroll
            for (int j = 0; j < 8; ++j) {
                const int k = 8 * lg + j + 32 * s;
                float v = 0.f;
                if (h < HD) {
                    if (k < HD)            v = wih[r * HD + k];
                    else if (k < 2 * HD)   v = whh[r * HD + (k - HD)];
                    else if (k == 2 * HD)  v = bi[r] + bh[r];
                }
                a[j] = (_Float16)v;
            }
            Af[s] = a;
        }
    }

    float* op = out + (b0 + rl) * (size_t)TT * HD + hh;

    // ---- x-prefetch: waves 0-8, lanes 0-31, one element each (2-deep hold) ----
    const int  pfe = wid * 32 + lane;
    const bool pv  = (lane < 32) && (pfe < NB * HD);
    const int  pb  = pv ? pfe / HD : 0;
    const int  pk  = pv ? pfe % HD : 0;
    const float* xpp = x + (b0 + pb) * (size_t)TT * HD + pk;
    float xh = 0.f, xn2 = 0.f;
    if (pv) { xh = xpp[3 * HD]; xn2 = xpp[4 * HD]; }

    __syncthreads();

    float cst = 0.f;

    for (int n = 0; n <= TT; ++n) {
        const bool active = isl1 ? (n < TT) : (n >= 1);
        if (active) {
            const int bufi = isl1 ? (n & 3) : (4 + (n & 1));
            const _Float16* rowp = &SH[bufi][rl][0];
            v8h Bf[2];
            #pragma unroll
            for (int s = 0; s < 2; ++s) {
                union { uint2 u[2]; v8h v; } cv;
                cv.u[0] = *(const uint2*)(rowp + 8 * lg + 32 * s);
                cv.u[1] = *(const uint2*)(rowp + 8 * lg + 32 * s + 4);
                Bf[s] = cv.v;
            }
            v4f acc = {0.f, 0.f, 0.f, 0.f};
            acc = __builtin_amdgcn_mfma_f32_16x16x32_f16(Af[0], Bf[0], acc, 0, 0, 0);
            acc = __builtin_amdgcn_mfma_f32_16x16x32_f16(Af[1], Bf[1], acc, 0, 0, 0);

            const float gi = fsig(acc[0]);
            const float gf = fsig(acc[1]);
            const float gg = 2.f * fsig(2.f * acc[2]) - 1.f;   // tanh
            const float go = fsig(acc[3]);
            cst = gf * cst + gi * gg;
            const float th = 2.f * fsig(2.f * cst) - 1.f;
            const float hv = go * th;
            const _Float16 h16 = (_Float16)hv;

            const int wb1 = (n + 1) & 3;
            const int wb2 = 4 + ((n + 1) & 1);
            if (hh < HD) {
                if (isl1) {
                    SH[wb1][rl][HD + hh] = h16;    // h1 -> own recurrence
                    SH[wb2][rl][hh]      = h16;    // h1 -> layer-2 input
                } else {
                    SH[wb2][rl][HD + hh] = h16;    // h2 -> own recurrence
                    op[(size_t)(n - 1) * HD] = hv; // final output h2[n-1]
                }
            }
        }
        // ---- x staging: store x[n+3] (loaded 2 iters ago), load x[n+5] ----
        if (pv) {
            if (n + 3 < TT) SH[(n + 3) & 3][pb][pk] = (_Float16)xh;
            xh = xn2;
            if (n + 5 < TT) xn2 = xpp[(size_t)(n + 5) * HD];
        }
        __syncthreads();
    }
}

extern "C" void kernel_launch(void* const* d_in, const int* in_sizes, int n_in,
                              void* d_out, int out_size, void* d_ws, size_t ws_size,
                              hipStream_t stream) {
    const float* x    = (const float*)d_in[0];
    const float* wih0 = (const float*)d_in[1];
    const float* whh0 = (const float*)d_in[2];
    const float* bih0 = (const float*)d_in[3];
    const float* bhh0 = (const float*)d_in[4];
    const float* wih1 = (const float*)d_in[5];
    const float* whh1 = (const float*)d_in[6];
    const float* bih1 = (const float*)d_in[7];
    const float* bhh1 = (const float*)d_in[8];
    float* out = (float*)d_out;
    (void)d_ws; (void)ws_size; (void)in_sizes; (void)n_in; (void)out_size;

    lstm2_mfma10<<<dim3(4096 / NB), dim3(NTH), 0, stream>>>(
        x, wih0, whh0, bih0, bhh0, wih1, whh1, bih1, bhh1, out);
}

// Round 8
// 297.168 us; speedup vs baseline: 1.6589x; 1.6589x over previous
//
#include <hip/hip_runtime.h>

#define TT   512
#define HD   18
#define NB   16          /* batches per block */
#define NTH  256         /* 4 waves */
#define RS   68          /* LDS row stride in halves (136B: 8B-aligned, odd dwords) */

typedef _Float16 v8h __attribute__((ext_vector_type(8)));
typedef float    v4f __attribute__((ext_vector_type(4)));

__device__ __forceinline__ float fsig(float x) {
    return __builtin_amdgcn_rcpf(1.0f + __expf(-x));
}

// Barrier WITHOUT vmcnt drain: LDS producer->consumer only needs lgkmcnt(0).
// Global loads/stores stay in flight across it (T3/T4 pattern).
__device__ __forceinline__ void softbar() {
    asm volatile("s_waitcnt lgkmcnt(0)" ::: "memory");
    __builtin_amdgcn_s_barrier();
    __builtin_amdgcn_sched_barrier(0);
}

// LDS rows (per buffer, per batch): k[0..17]=input (x or h1), k[18..35]=own h,
// k[36]=1.0 (bias column), k[37..67]=0.
// Buffers: SH[0..3] = layer-1 ring (x 3-ahead, h1 1-ahead); SH[4..5] = layer-2 dbuf.

template<int NT>
__device__ __forceinline__ void run_wave(
    int tbase, int isl1, int pfmode, int lane,
    const float* __restrict__ x,
    const float* __restrict__ wih, const float* __restrict__ whh,
    const float* __restrict__ bi,  const float* __restrict__ bh,
    float* __restrict__ out,
    _Float16 (*SH)[NB][RS], size_t b0)
{
    const int rl = lane & 15;       // batch column
    const int lg = lane >> 4;       // k-group / h-subrow

    // ---- A fragments: W'[row=4h+g][k] , k: 0-17 wih, 18-35 whh, 36 bias ----
    v8h Af[NT][2];
    int hh[NT];
    #pragma unroll
    for (int i = 0; i < NT; ++i) {
        const int row = 16 * (tbase + i) + rl;
        const int h = row >> 2, g = row & 3;
        const int r = g * HD + h;
        #pragma unroll
        for (int s = 0; s < 2; ++s) {
            v8h a;
            #pragma unroll
            for (int j = 0; j < 8; ++j) {
                const int k = 8 * lg + j + 32 * s;
                float v = 0.f;
                if (h < HD) {
                    if (k < HD)            v = wih[r * HD + k];
                    else if (k < 2 * HD)   v = whh[r * HD + (k - HD)];
                    else if (k == 2 * HD)  v = bi[r] + bh[r];
                }
                a[j] = (_Float16)v;
            }
            Af[i][s] = a;
        }
        hh[i] = 4 * (tbase + i) + lg;   // this lane's h for tile i (C-layout)
    }

    // output pointers (used by layer-2 waves)
    float* op[NT];
    #pragma unroll
    for (int i = 0; i < NT; ++i)
        op[i] = out + (b0 + rl) * (size_t)TT * HD + hh[i];

    // ---- x-prefetch lane assignments (fixed elements) ----
    int pb[3] = {0,0,0}, pk[3] = {0,0,0}; bool pv[3] = {false,false,false};
    float xpf[3] = {0.f, 0.f, 0.f};
    if (pfmode) {
        int ee[3];
        ee[0] = (pfmode == 1) ? lane       : 128 + lane;
        ee[1] = (pfmode == 1) ? 64 + lane  : 192 + lane;
        ee[2] = (pfmode == 1) ? 256 + lane : 999;
        #pragma unroll
        for (int j = 0; j < 3; ++j) {
            pv[j] = ee[j] < NB * HD;
            pb[j] = pv[j] ? ee[j] / HD : 0;
            pk[j] = pv[j] ? ee[j] % HD : 0;
            if (pv[j])   // preload x[3]
                xpf[j] = x[(b0 + pb[j]) * (size_t)TT * HD + 3 * HD + pk[j]];
        }
    }

    float cst[NT];
    #pragma unroll
    for (int i = 0; i < NT; ++i) cst[i] = 0.f;

    for (int n = 0; n <= TT; ++n) {
        // ---- issue next x loads FIRST (in flight across the whole body;
        //      consumed by the ds_write one iteration from now) ----
        float xnew[3] = {0.f, 0.f, 0.f};
        if (pfmode && (n + 4) < TT) {
            #pragma unroll
            for (int j = 0; j < 3; ++j)
                if (pv[j]) xnew[j] = x[(b0 + pb[j]) * (size_t)TT * HD
                                       + (size_t)(n + 4) * HD + pk[j]];
        }

        const bool active = isl1 ? (n < TT) : (n >= 1);
        if (active) {
            const int bufi = isl1 ? (n & 3) : (4 + (n & 1));
            const _Float16* rowp = &SH[bufi][rl][0];
            v8h Bf[2];
            #pragma unroll
            for (int s = 0; s < 2; ++s) {
                union { uint2 u[2]; v8h v; } cv;
                cv.u[0] = *(const uint2*)(rowp + 8 * lg + 32 * s);
                cv.u[1] = *(const uint2*)(rowp + 8 * lg + 32 * s + 4);
                Bf[s] = cv.v;
            }
            const int wb1 = (n + 1) & 3;        // L1 ring slot for h1[n]
            const int wb2 = 4 + ((n + 1) & 1);  // L2 dbuf slot for next iter
            #pragma unroll
            for (int i = 0; i < NT; ++i) {
                v4f acc = {0.f, 0.f, 0.f, 0.f};
                acc = __builtin_amdgcn_mfma_f32_16x16x32_f16(Af[i][0], Bf[0], acc, 0, 0, 0);
                acc = __builtin_amdgcn_mfma_f32_16x16x32_f16(Af[i][1], Bf[1], acc, 0, 0, 0);
                const float gi = fsig(acc[0]);
                const float gf = fsig(acc[1]);
                const float gg = 2.f * fsig(2.f * acc[2]) - 1.f;   // tanh
                const float go = fsig(acc[3]);
                cst[i] = gf * cst[i] + gi * gg;
                const float th = 2.f * fsig(2.f * cst[i]) - 1.f;
                const float hv = go * th;
                const _Float16 h16 = (_Float16)hv;
                if (hh[i] < HD) {
                    if (isl1) {
                        SH[wb1][rl][HD + hh[i]] = h16;   // h1 -> own recurrence
                        SH[wb2][rl][hh[i]]      = h16;   // h1 -> layer-2 input
                    } else {
                        SH[wb2][rl][HD + hh[i]] = h16;   // h2 -> own recurrence
                        op[i][(size_t)(n - 1) * HD] = hv;  // output (fire-and-forget)
                    }
                }
            }
        }
        // ---- x staging: store x[n+3] (loaded one iteration ago) ----
        if (pfmode) {
            if (n + 3 < TT) {
                const int xb = (n + 3) & 3;
                #pragma unroll
                for (int j = 0; j < 3; ++j)
                    if (pv[j]) SH[xb][pb[j]][pk[j]] = (_Float16)xpf[j];
            }
            #pragma unroll
            for (int j = 0; j < 3; ++j) xpf[j] = xnew[j];
        }
        softbar();
    }
}

__global__ __launch_bounds__(NTH) void lstm2_mfma_nb(
    const float* __restrict__ x,
    const float* __restrict__ wih0, const float* __restrict__ whh0,
    const float* __restrict__ bih0, const float* __restrict__ bhh0,
    const float* __restrict__ wih1, const float* __restrict__ whh1,
    const float* __restrict__ bih1, const float* __restrict__ bhh1,
    float* __restrict__ out)
{
    __shared__ __align__(16) _Float16 SH[6][NB][RS];

    const int tid  = threadIdx.x;
    const int wid  = tid >> 6;
    const int lane = tid & 63;
    const size_t b0 = (size_t)blockIdx.x * NB;

    // ---- init: zero everything, set bias columns, fill x[0..2] ----
    {
        uint* shw = (uint*)&SH[0][0][0];            // 6*16*68/2 = 3264 dwords
        for (int i = tid; i < 6 * NB * RS / 2; i += NTH) shw[i] = 0u;
        __syncthreads();
        for (int i = tid; i < 6 * NB; i += NTH)
            SH[i / NB][i % NB][2 * HD] = (_Float16)1.0f;
        for (int i = tid; i < 3 * NB * HD; i += NTH) {
            const int t = i / (NB * HD), r2 = i % (NB * HD);
            const int b = r2 / HD, k = r2 % HD;
            SH[t][b][k] = (_Float16)x[(b0 + b) * (size_t)TT * HD + t * HD + k];
        }
        __syncthreads();
    }

    if      (wid == 0) run_wave<3>(0, 1, 0, lane, x, wih0, whh0, bih0, bhh0, out, SH, b0);
    else if (wid == 1) run_wave<2>(3, 1, 1, lane, x, wih0, whh0, bih0, bhh0, out, SH, b0);
    else if (wid == 2) run_wave<3>(0, 0, 0, lane, x, wih1, whh1, bih1, bhh1, out, SH, b0);
    else               run_wave<2>(3, 0, 2, lane, x, wih1, whh1, bih1, bhh1, out, SH, b0);
}

extern "C" void kernel_launch(void* const* d_in, const int* in_sizes, int n_in,
                              void* d_out, int out_size, void* d_ws, size_t ws_size,
                              hipStream_t stream) {
    const float* x    = (const float*)d_in[0];
    const float* wih0 = (const float*)d_in[1];
    const float* whh0 = (const float*)d_in[2];
    const float* bih0 = (const float*)d_in[3];
    const float* bhh0 = (const float*)d_in[4];
    const float* wih1 = (const float*)d_in[5];
    const float* whh1 = (const float*)d_in[6];
    const float* bih1 = (const float*)d_in[7];
    const float* bhh1 = (const float*)d_in[8];
    float* out = (float*)d_out;
    (void)d_ws; (void)ws_size; (void)in_sizes; (void)n_in; (void)out_size;

    lstm2_mfma_nb<<<dim3(4096 / NB), dim3(NTH), 0, stream>>>(
        x, wih0, whh0, bih0, bhh0, wih1, whh1, bih1, bhh1, out);
}